// Round 2
// baseline (162.550 us; speedup 1.0000x reference)
//
#include <hip/hip_runtime.h>
#include <hip/hip_bf16.h>
#include <cstdint>
#include <cstddef>

#define BB   64
#define CINN 64
#define TS   4096
#define FF   128
#define KS   64
#define TOUT (TS - KS + 1)   // 4033

// ---- fused-kernel tiling ----
#define TSEG 256             // outputs per tile (= one 256-output banded-MFMA tile)
#define XROW 320             // t-extent of staged x / computed y (TSEG + KS)
#define SXTW 35              // xT row stride in u32: 32 data cols + 3 pad (col 32/33 = sq->rinv)
#define YW   336             // yL cols: XROW + 16 finite-pad (zeroed; band coeffs there are 0)
#define YWW  (YW / 2)        // 168 u32 words per yL row (672 B, 16B-aligned rows)

typedef __attribute__((ext_vector_type(8))) short short8;
typedef __attribute__((ext_vector_type(4))) float f32x4;
union FragU { unsigned int u[4]; short8 v; uint4 q4; };

static __device__ __forceinline__ unsigned int f2bf_u(float f) {
    __hip_bfloat16 h = __float2bfloat16(f);
    return (unsigned int)*reinterpret_cast<unsigned short*>(&h);
}

// ---- Setup: banded temporal-B fragments (R5/R6-validated) + sw bf16 fragments +
//      fused norm weights ----
// bandB[(f*3+s)*64 + lane] = 8 bf16: B_s[k=8q+j][n] = cw[32s+k-n] (0 outside [0,64))
// swF[(ft*2+s)*64 + lane]  = 8 bf16: sw[16ft+(l&15)][32s+8q+j]  (B-operand frag, N=filter)
__global__ void k_band(const float* __restrict__ cw, const float* __restrict__ sw,
                       const float* __restrict__ weight,
                       uint4* __restrict__ bandB, float* __restrict__ wnf,
                       uint4* __restrict__ swF) {
    const int f = blockIdx.x, l = threadIdx.x;
    const int n = l & 15, q = l >> 4;
    for (int s = 0; s < 3; ++s) {
        FragU o;
#pragma unroll
        for (int i = 0; i < 4; ++i) {
            int i0 = 32 * s + 8 * q + 2 * i - n;
            int i1 = i0 + 1;
            float a = (i0 >= 0 && i0 < KS) ? cw[(size_t)f * KS + i0] : 0.f;
            float c = (i1 >= 0 && i1 < KS) ? cw[(size_t)f * KS + i1] : 0.f;
            o.u[i] = f2bf_u(a) | (f2bf_u(c) << 16);
        }
        bandB[((size_t)f * 3 + s) * 64 + l] = o.q4;
    }
    // sw bf16 fragments: blocks f = 0,16,32,... build filter-tile ft = f>>4
    if ((f & 15) == 0) {
        const int ft = f >> 4;
        for (int s = 0; s < 2; ++s) {
            FragU o;
#pragma unroll
            for (int i = 0; i < 4; ++i) {
                const float* sr = sw + (size_t)(16 * ft + n) * CINN + 32 * s + 8 * q + 2 * i;
                o.u[i] = f2bf_u(sr[0]) | (f2bf_u(sr[1]) << 16);
            }
            swF[((size_t)ft * 2 + s) * 64 + l] = o.q4;
        }
    }
    // per-filter weight * rsqrt(|sw_f|^2 * |cw_f|^2) * scale / TOUT
    float a = sw[(size_t)f * CINN + l], c = cw[(size_t)f * KS + l];
    float v = a * a, u = c * c;
    for (int off = 32; off > 0; off >>= 1) {
        v += __shfl_down(v, off, 64);
        u += __shfl_down(u, off, 64);
    }
    if (l == 0) wnf[f] = weight[f] * rsqrtf(v * u) * (64.0f / (float)TOUT);
}

// ============ Persistent fused kernel: 4 adjacent t-tiles per block ============
// Block = 4 t-tiles x one batch; grid (4, BB) = 256 blocks = 1/CU (LDS 128 KiB).
// Spatial GEMM uses SWAPPED MFMA operands: D[t][filter] -> lane-local bf16 pack,
// ds_write_b64, zero cross-lane shuffles. Next tile's x is prefetched into
// registers during phase 3 (issue-early / write-late).
__global__ __launch_bounds__(1024, 4) void k_fused(
    const float* __restrict__ x, const uint4* __restrict__ swF,
    const uint4* __restrict__ bandB, const float* __restrict__ wnf,
    const float* __restrict__ bias, float* __restrict__ out)
{
    __shared__ unsigned int xT[XROW * SXTW];   // 44,800 B
    __shared__ unsigned int yL[FF * YWW];      // 86,016 B (rows 0..30 reused as sq partials)
    __shared__ float wred[16];

    const int tid = threadIdx.x;
    const int w = tid >> 6, l = tid & 63;
    const int m = l & 15, q = l >> 4;
    const int b = blockIdx.y;
    const int g = blockIdx.x;                  // 0..3 -> t-tiles 4g..4g+3

    const float* xb = x + (size_t)b * CINN * TS;

    // ---- preload this wave's 8 sw fragments (filter-quad = w&1) ----
    FragU swf[4][2];
    {
        const int quad = w & 1;
#pragma unroll
        for (int fi = 0; fi < 4; ++fi)
#pragma unroll
            for (int s = 0; s < 2; ++s)
                swf[fi][s].q4 = swF[((size_t)(4 * quad + fi) * 2 + s) * 64 + l];
    }

    // ---- x prefetch registers (main 256-t segment; tail loaded in-phase) ----
    float4 xa[2][2];
    auto loadx = [&](int tb) {
#pragma unroll
        for (int r = 0; r < 2; ++r) {
            const int cp = w + 16 * r;
            const float* x0 = xb + (size_t)(2 * cp) * TS;
            int p = tb + 4 * l; if (p > TS - 4) p = TS - 4;
            xa[r][0] = *(const float4*)(x0 + p);
            xa[r][1] = *(const float4*)(x0 + TS + p);
        }
    };
    loadx(4 * g * TSEG);

    float acc = 0.f;

    for (int tile = 0; tile < 4; ++tile) {
        const int t0 = (4 * g + tile) * TSEG;

        // ---------- Phase 1: write staged x -> xT (bf16 ch-pairs) + sq partials ----------
        {
            float* sqp = (float*)yL;           // [16][XROW] f32 partials
            float4 s4a = {0.f, 0.f, 0.f, 0.f}, s4b = {0.f, 0.f, 0.f, 0.f};
#pragma unroll
            for (int r = 0; r < 2; ++r) {
                const int cp = w + 16 * r;
                float4 v0 = xa[r][0], v1 = xa[r][1];
                s4a.x += v0.x * v0.x + v1.x * v1.x;
                s4a.y += v0.y * v0.y + v1.y * v1.y;
                s4a.z += v0.z * v0.z + v1.z * v1.z;
                s4a.w += v0.w * v0.w + v1.w * v1.w;
                const int t = 4 * l;
                xT[(t + 0) * SXTW + cp] = f2bf_u(v0.x) | (f2bf_u(v1.x) << 16);
                xT[(t + 1) * SXTW + cp] = f2bf_u(v0.y) | (f2bf_u(v1.y) << 16);
                xT[(t + 2) * SXTW + cp] = f2bf_u(v0.z) | (f2bf_u(v1.z) << 16);
                xT[(t + 3) * SXTW + cp] = f2bf_u(v0.w) | (f2bf_u(v1.w) << 16);
            }
            if (l < 16) {                      // tail t-local 256..319, direct load
#pragma unroll
                for (int r = 0; r < 2; ++r) {
                    const int cp = w + 16 * r;
                    const float* x0 = xb + (size_t)(2 * cp) * TS;
                    int p = t0 + 256 + 4 * l; if (p > TS - 4) p = TS - 4;
                    float4 v0 = *(const float4*)(x0 + p);
                    float4 v1 = *(const float4*)(x0 + TS + p);
                    s4b.x += v0.x * v0.x + v1.x * v1.x;
                    s4b.y += v0.y * v0.y + v1.y * v1.y;
                    s4b.z += v0.z * v0.z + v1.z * v1.z;
                    s4b.w += v0.w * v0.w + v1.w * v1.w;
                    const int t = 256 + 4 * l;
                    xT[(t + 0) * SXTW + cp] = f2bf_u(v0.x) | (f2bf_u(v1.x) << 16);
                    xT[(t + 1) * SXTW + cp] = f2bf_u(v0.y) | (f2bf_u(v1.y) << 16);
                    xT[(t + 2) * SXTW + cp] = f2bf_u(v0.z) | (f2bf_u(v1.z) << 16);
                    xT[(t + 3) * SXTW + cp] = f2bf_u(v0.w) | (f2bf_u(v1.w) << 16);
                }
            }
            *(float4*)(sqp + w * XROW + 4 * l) = s4a;
            if (l < 16) *(float4*)(sqp + w * XROW + 256 + 4 * l) = s4b;
        }
        __syncthreads();

        // ---------- Phase 2: reduce sq partials into xT pad col 32 ----------
        if (tid < XROW) {
            const float* sqp = (const float*)yL;
            float s = 0.f;
#pragma unroll
            for (int w2 = 0; w2 < 16; ++w2) s += sqp[w2 * XROW + tid];
            xT[tid * SXTW + 32] = __float_as_uint(s);
        }
        __syncthreads();

        // ---------- Phase 3a (wave 15): sliding-window rinv -> xT pad cols 32/33 ----------
        // Lockstep-safe within the wave: all window reads precede the scatter stores.
        if (w == 15 && l < 32) {
            const int base = 8 * l;
            float s = 0.f, hd[8], tl[8];
#pragma unroll
            for (int k = 0; k < 64; ++k) {
                float v = __uint_as_float(xT[(base + k) * SXTW + 32]);
                if (k < 8) hd[k] = v;
                s += v;
            }
#pragma unroll
            for (int j = 0; j < 8; ++j) tl[j] = __uint_as_float(xT[(base + 64 + j) * SXTW + 32]);
            float rv[8];
#pragma unroll
            for (int j = 0; j < 8; ++j) {
                int tpos = t0 + base + j;
                rv[j] = (tpos < TOUT) ? rsqrtf(s) : 0.f;   // masks tail outputs
                s += tl[j] - hd[j];
            }
#pragma unroll
            for (int j = 0; j < 8; ++j) {
                int t = base + j;
                xT[t * SXTW + 32 + ((t >> 6) & 1)] = __float_as_uint(rv[j]);
            }
        }

        // ---------- Phase 3b: spatial GEMM, swapped operands: D[t][filter] ----------
        // mfma(x_frag, sw_frag): M=t (rows, 4 consecutive per lane), N=filter (cols).
        // Pack (t,t+1) bf16 pairs lane-locally; one ds_write_b64 per filter-tile. No shfl.
        {
            const int quad = w & 1;
            for (int tt = (w >> 1); tt < 20; tt += 8) {
                const int bw = (16 * tt + m) * SXTW + 4 * q;
                FragU b0, b1;
#pragma unroll
                for (int i = 0; i < 4; ++i) { b0.u[i] = xT[bw + i]; b1.u[i] = xT[bw + 16 + i]; }
#pragma unroll
                for (int fi = 0; fi < 4; ++fi) {
                    f32x4 d = {0.f, 0.f, 0.f, 0.f};
                    d = __builtin_amdgcn_mfma_f32_16x16x32_bf16(b0.v, swf[fi][0].v, d, 0, 0, 0);
                    d = __builtin_amdgcn_mfma_f32_16x16x32_bf16(b1.v, swf[fi][1].v, d, 0, 0, 0);
                    const int f = 16 * (4 * quad + fi) + m;
                    uint2 o;
                    o.x = f2bf_u(d[0]) | (f2bf_u(d[1]) << 16);   // t = 16tt+4q, +1
                    o.y = f2bf_u(d[2]) | (f2bf_u(d[3]) << 16);   // t = 16tt+4q+2, +3
                    *(uint2*)(yL + f * YWW + 8 * tt + 2 * q) = o;
                }
            }
            // zero the finite-pad cols 320..335 (multiplied by band zeros; must be finite)
            yL[(tid >> 3) * YWW + 160 + (tid & 7)] = 0u;
        }

        // ---- issue next tile's x loads (consumed after next barrier pair) ----
        if (tile < 3) loadx(t0 + TSEG);
        __syncthreads();

        // ---------- Phase 4: banded temporal MFMA, A-frags from yL (ds_read_b128) ----------
        {
            float rr[4];
#pragma unroll
            for (int r = 0; r < 4; ++r) {
                int t = 64 * q + 16 * r + m;   // this lane's 4 output positions
                rr[r] = __uint_as_float(xT[t * SXTW + 32 + (q & 1)]);
            }
            const int f0t = 8 * w;
            uint4 pb0, pb1, pb2;
            {
                const uint4* bb = bandB + (size_t)f0t * 3 * 64;
                pb0 = bb[l]; pb1 = bb[64 + l]; pb2 = bb[128 + l];
            }
#pragma unroll 2
            for (int fi = 0; fi < 8; ++fi) {
                const int f = f0t + fi;
                FragU B0, B1, B2;
                B0.q4 = pb0; B1.q4 = pb1; B2.q4 = pb2;
                if (fi < 7) {                  // prefetch next filter's band (L2)
                    const uint4* bb = bandB + (size_t)(f + 1) * 3 * 64;
                    pb0 = bb[l]; pb1 = bb[64 + l]; pb2 = bb[128 + l];
                }
                const int abase = f * YWW + 8 * m + 4 * q;   // 16B-aligned u32 word index
                FragU a0, a1, a2;
                a0.q4 = *(const uint4*)(yL + abase);
                a1.q4 = *(const uint4*)(yL + abase + 16);
                a2.q4 = *(const uint4*)(yL + abase + 32);
                f32x4 d = {0.f, 0.f, 0.f, 0.f};
                d = __builtin_amdgcn_mfma_f32_16x16x32_bf16(a0.v, B0.v, d, 0, 0, 0);
                d = __builtin_amdgcn_mfma_f32_16x16x32_bf16(a1.v, B1.v, d, 0, 0, 0);
                d = __builtin_amdgcn_mfma_f32_16x16x32_bf16(a2.v, B2.v, d, 0, 0, 0);
                float facc = 0.f;
#pragma unroll
                for (int r = 0; r < 4; ++r) facc += fabsf(d[r]) * rr[r];
                acc += wnf[f] * facc;
            }
        }
        __syncthreads();                       // protects xT/yL for next tile's phase 1
    }

    // ---------- epilogue: block reduction + one atomic ----------
    for (int off = 32; off > 0; off >>= 1) acc += __shfl_down(acc, off, 64);
    if (l == 0) wred[w] = acc;
    __syncthreads();
    if (tid == 0) {
        float s = 0.f;
#pragma unroll
        for (int i = 0; i < 16; ++i) s += wred[i];
        atomicAdd(out + b, s);
    }
    if (g == 0 && tid < FF) {
        float v = bias[tid];
        for (int off = 32; off > 0; off >>= 1) v += __shfl_down(v, off, 64);
        if ((tid & 63) == 0) atomicAdd(out + b, v);
    }
}

// --------- Fallback (no workspace): one block per (f,b), LDS rows ----------
__global__ __launch_bounds__(256) void k_naive(
    const float* __restrict__ x, const float* __restrict__ cw,
    const float* __restrict__ sw, const float* __restrict__ weight,
    const float* __restrict__ bias, float* __restrict__ out)
{
    __shared__ float yl[TS];
    __shared__ float ql[TS];
    __shared__ float wred[4];
    const int f = blockIdx.x, b = blockIdx.y, tid = threadIdx.x;
    for (int t = tid; t < TS; t += 256) {
        float a = 0.f, s = 0.f;
        for (int c = 0; c < CINN; ++c) {
            float v = x[((size_t)b * CINN + c) * TS + t];
            a += sw[(size_t)f * CINN + c] * v;
            s += v * v;
        }
        yl[t] = a; ql[t] = s;
    }
    __syncthreads();
    float acc = 0.f;
    for (int t = tid; t < TOUT; t += 256) {
        float cv = 0.f, sl = 0.f;
        for (int k = 0; k < KS; ++k) { cv += cw[(size_t)f * KS + k] * yl[t + k]; sl += ql[t + k]; }
        acc += fabsf(cv) * rsqrtf(sl);
    }
    float ssw = 0.f, scw = 0.f;
    for (int c = 0; c < CINN; ++c) { float v = sw[(size_t)f * CINN + c]; ssw += v * v; }
    for (int k = 0; k < KS; ++k)   { float v = cw[(size_t)f * KS + k];  scw += v * v; }
    const float wnf = weight[f] * rsqrtf(ssw * scw) * 64.0f / (float)TOUT;
    for (int off = 32; off > 0; off >>= 1) acc += __shfl_down(acc, off, 64);
    if ((tid & 63) == 0) wred[tid >> 6] = acc;
    __syncthreads();
    if (tid == 0) {
        float tot = (wred[0] + wred[1] + wred[2] + wred[3]) * wnf;
        if (f == 0) {
            float bsum = 0.f;
            for (int ff = 0; ff < FF; ++ff) bsum += bias[ff];
            tot += bsum;
        }
        atomicAdd(out + b, tot);
    }
}

extern "C" void kernel_launch(void* const* d_in, const int* in_sizes, int n_in,
                              void* d_out, int out_size, void* d_ws, size_t ws_size,
                              hipStream_t stream) {
    const float* x  = (const float*)d_in[0];
    const float* cw = (const float*)d_in[1];   // [F,K]
    const float* sw = (const float*)d_in[2];   // [F,CIN]
    const float* w  = (const float*)d_in[3];   // [F]
    const float* bs = (const float*)d_in[4];   // [F]
    float* out = (float*)d_out;

    hipMemsetAsync(d_out, 0, (size_t)out_size * sizeof(float), stream);

    const size_t bandBytes = (size_t)FF * 3 * 64 * 16;       // 384 KB
    const size_t wnBytes   = (size_t)FF * sizeof(float);
    const size_t swfBytes  = (size_t)(FF / 16) * 2 * 64 * 16; // 16 KB

    if (bandBytes + wnBytes + swfBytes <= ws_size) {
        uint4* bandB = (uint4*)d_ws;
        float* wnf   = (float*)((char*)d_ws + bandBytes);
        uint4* swF   = (uint4*)((char*)d_ws + bandBytes + wnBytes);
        k_band <<<dim3(FF), 64, 0, stream>>>(cw, sw, w, bandB, wnf, swF);
        k_fused<<<dim3(4, BB), 1024, 0, stream>>>(x, swF, bandB, wnf, bs, out);
    } else {
        k_naive<<<dim3(FF, BB), 256, 0, stream>>>(x, cw, sw, w, bs, out);
    }
}

// Round 3
// 136.089 us; speedup vs baseline: 1.1944x; 1.1944x over previous
//
#include <hip/hip_runtime.h>
#include <hip/hip_bf16.h>
#include <cstdint>
#include <cstddef>

#define BB   64
#define CINN 64
#define TS   4096
#define FF   128
#define KS   64
#define TOUT (TS - KS + 1)   // 4033

// ---- fused-kernel tiling ----
#define TSEG 256             // outputs per block (= one 256-output banded-MFMA tile)
#define XROW 320             // t-extent of staged x / computed y (TSEG + KS)
#define SXW  324             // xT row stride in u32 words (mult of 4 -> b128-aligned rows)
#define YW   336             // yL cols: XROW + 16 finite-pad (zeroed; band coeffs there are 0)
#define YWW  (YW / 2)        // 168 u32 words per yL row (672 B, 16B-aligned rows)

typedef __attribute__((ext_vector_type(8))) short short8;
typedef __attribute__((ext_vector_type(4))) float f32x4;
union FragU { unsigned int u[4]; short8 v; uint4 q4; };

static __device__ __forceinline__ unsigned int f2bf_u(float f) {
    __hip_bfloat16 h = __float2bfloat16(f);
    return (unsigned int)*reinterpret_cast<unsigned short*>(&h);
}

// ---- Setup: banded temporal-B fragments (R5/R6-validated) + sw bf16 fragments +
//      fused norm weights ----
// bandB[(f*3+s)*64 + lane] = 8 bf16: B_s[k=8q+j][n] = cw[32s+k-n] (0 outside [0,64))
// swF[(ft*2+s)*64 + lane]  = 8 bf16: sw[16ft+(l&15)][32s+8q+j]  (B-operand frag, N=filter)
__global__ void k_band(const float* __restrict__ cw, const float* __restrict__ sw,
                       const float* __restrict__ weight,
                       uint4* __restrict__ bandB, float* __restrict__ wnf,
                       uint4* __restrict__ swF) {
    const int f = blockIdx.x, l = threadIdx.x;
    const int n = l & 15, q = l >> 4;
    for (int s = 0; s < 3; ++s) {
        FragU o;
#pragma unroll
        for (int i = 0; i < 4; ++i) {
            int i0 = 32 * s + 8 * q + 2 * i - n;
            int i1 = i0 + 1;
            float a = (i0 >= 0 && i0 < KS) ? cw[(size_t)f * KS + i0] : 0.f;
            float c = (i1 >= 0 && i1 < KS) ? cw[(size_t)f * KS + i1] : 0.f;
            o.u[i] = f2bf_u(a) | (f2bf_u(c) << 16);
        }
        bandB[((size_t)f * 3 + s) * 64 + l] = o.q4;
    }
    // sw bf16 fragments: blocks f = 0,16,32,... build filter-tile ft = f>>4
    if ((f & 15) == 0) {
        const int ft = f >> 4;
        for (int s = 0; s < 2; ++s) {
            FragU o;
#pragma unroll
            for (int i = 0; i < 4; ++i) {
                const float* sr = sw + (size_t)(16 * ft + n) * CINN + 32 * s + 8 * q + 2 * i;
                o.u[i] = f2bf_u(sr[0]) | (f2bf_u(sr[1]) << 16);
            }
            swF[((size_t)ft * 2 + s) * 64 + l] = o.q4;
        }
    }
    // per-filter weight * rsqrt(|sw_f|^2 * |cw_f|^2) * scale / TOUT
    float a = sw[(size_t)f * CINN + l], c = cw[(size_t)f * KS + l];
    float v = a * a, u = c * c;
    for (int off = 32; off > 0; off >>= 1) {
        v += __shfl_down(v, off, 64);
        u += __shfl_down(u, off, 64);
    }
    if (l == 0) wnf[f] = weight[f] * rsqrtf(v * u) * (64.0f / (float)TOUT);
}

// ============ Fused kernel: one 256-output tile per block, y never in HBM ============
// xT layout: [ch-pair 0..31][t 0..319] row stride 324 words; row 32 = sq, row 33 = rinv.
// Staging writes are ONE aligned ds_write_b128 per (thread, ch-pair): 64 lanes cover
// 256 contiguous words -> bank-uniform, conflict-free (was 8-way conflicted b32).
// Spatial GEMM: swapped operands mfma(x_frag, sw_frag) -> D[t][filter], lane-local
// bf16 pack, ds_write_b64, zero shuffles (R2-validated numerics).
// swF staged once into LDS; fragments read per-fi (unroll 1) -> no register pressure.
__global__ __launch_bounds__(1024, 4) void k_fused(
    const float* __restrict__ x, const uint4* __restrict__ swF,
    const uint4* __restrict__ bandB, const float* __restrict__ wnf,
    const float* __restrict__ bias, float* __restrict__ out)
{
    __shared__ unsigned int xT[34 * SXW];   // 44,064 B
    __shared__ uint4 swFl[1024];            // 16,384 B
    __shared__ unsigned int yL[FF * YWW];   // 86,016 B (words 0..5119 reused as sq partials)
    __shared__ float wred[16];

    const int tid = threadIdx.x;
    const int w = tid >> 6, l = tid & 63;
    const int m = l & 15, q = l >> 4;
    const int b = blockIdx.y;
    const int t0 = blockIdx.x * TSEG;

    swFl[tid] = swF[tid];                   // 16 KB sw-fragment stash (L2 -> LDS)

    // ---------- Phase 1: stage xT (bf16 ch-pairs, [cp][t]) + per-wave sq partials ----------
    {
        const float* xb = x + (size_t)b * CINN * TS;
        float* sqp = (float*)yL;            // [16][XROW] f32 partials
        float4 s4a = {0.f, 0.f, 0.f, 0.f}, s4b = {0.f, 0.f, 0.f, 0.f};
#pragma unroll
        for (int r = 0; r < 2; ++r) {
            const int cp = w + 16 * r;      // channel pair (2cp, 2cp+1)
            const float* x0 = xb + (size_t)(2 * cp) * TS;
            {
                int p = t0 + 4 * l; if (p > TS - 4) p = TS - 4;   // tail clamp (finite dups)
                float4 v0 = *(const float4*)(x0 + p);
                float4 v1 = *(const float4*)(x0 + TS + p);
                s4a.x += v0.x * v0.x + v1.x * v1.x;
                s4a.y += v0.y * v0.y + v1.y * v1.y;
                s4a.z += v0.z * v0.z + v1.z * v1.z;
                s4a.w += v0.w * v0.w + v1.w * v1.w;
                FragU o;
                o.u[0] = f2bf_u(v0.x) | (f2bf_u(v1.x) << 16);
                o.u[1] = f2bf_u(v0.y) | (f2bf_u(v1.y) << 16);
                o.u[2] = f2bf_u(v0.z) | (f2bf_u(v1.z) << 16);
                o.u[3] = f2bf_u(v0.w) | (f2bf_u(v1.w) << 16);
                *(uint4*)&xT[cp * SXW + 4 * l] = o.q4;            // aligned b128, uniform banks
            }
            if (l < 16) {                   // tail t-local 256..319
                int p = t0 + 256 + 4 * l; if (p > TS - 4) p = TS - 4;
                float4 v0 = *(const float4*)(x0 + p);
                float4 v1 = *(const float4*)(x0 + TS + p);
                s4b.x += v0.x * v0.x + v1.x * v1.x;
                s4b.y += v0.y * v0.y + v1.y * v1.y;
                s4b.z += v0.z * v0.z + v1.z * v1.z;
                s4b.w += v0.w * v0.w + v1.w * v1.w;
                FragU o;
                o.u[0] = f2bf_u(v0.x) | (f2bf_u(v1.x) << 16);
                o.u[1] = f2bf_u(v0.y) | (f2bf_u(v1.y) << 16);
                o.u[2] = f2bf_u(v0.z) | (f2bf_u(v1.z) << 16);
                o.u[3] = f2bf_u(v0.w) | (f2bf_u(v1.w) << 16);
                *(uint4*)&xT[cp * SXW + 256 + 4 * l] = o.q4;
            }
        }
        *(float4*)(sqp + w * XROW + 4 * l) = s4a;
        if (l < 16) *(float4*)(sqp + w * XROW + 256 + 4 * l) = s4b;
    }
    __syncthreads();

    // ---------- Phase 2: reduce sq partials into xT row 32 ----------
    if (tid < XROW) {
        const float* sqp = (const float*)yL;
        float s = 0.f;
#pragma unroll
        for (int i = 0; i < 16; ++i) s += sqp[i * XROW + tid];
        xT[32 * SXW + tid] = __float_as_uint(s);
    }
    __syncthreads();

    // ---------- Phase 3a (wave 15): sliding-window rinv: row 32 -> row 33 ----------
    // Disjoint src/dst rows: no read/write hazard within the wave.
    if (w == 15 && l < 32) {
        const int base = 8 * l;
        float s = 0.f, hd[8], tl[8];
#pragma unroll
        for (int k = 0; k < 64; ++k) {
            float v = __uint_as_float(xT[32 * SXW + base + k]);
            if (k < 8) hd[k] = v;
            s += v;
        }
#pragma unroll
        for (int j = 0; j < 8; ++j) tl[j] = __uint_as_float(xT[32 * SXW + base + 64 + j]);
#pragma unroll
        for (int j = 0; j < 8; ++j) {
            int tpos = t0 + base + j;
            float rv = (tpos < TOUT) ? rsqrtf(s) : 0.f;   // masks tail outputs
            xT[33 * SXW + base + j] = __float_as_uint(rv);
            s += tl[j] - hd[j];
        }
    }

    // ---------- Phase 3b: spatial GEMM, swapped operands: D[t][filter] ----------
    {
        const int quad = w & 1;
        for (int tt = (w >> 1); tt < 20; tt += 8) {
            FragU b0, b1;                   // x frags: A[t-row][k=ch], strided b32 reads (2-way)
#pragma unroll
            for (int i = 0; i < 4; ++i) {
                b0.u[i] = xT[(4 * q + i) * SXW + 16 * tt + m];
                b1.u[i] = xT[(16 + 4 * q + i) * SXW + 16 * tt + m];
            }
#pragma unroll 1
            for (int fi = 0; fi < 4; ++fi) {
                FragU s0, s1;               // transient sw frags from LDS stash
                s0.q4 = swFl[((4 * quad + fi) * 2 + 0) * 64 + l];
                s1.q4 = swFl[((4 * quad + fi) * 2 + 1) * 64 + l];
                f32x4 d = {0.f, 0.f, 0.f, 0.f};
                d = __builtin_amdgcn_mfma_f32_16x16x32_bf16(b0.v, s0.v, d, 0, 0, 0);
                d = __builtin_amdgcn_mfma_f32_16x16x32_bf16(b1.v, s1.v, d, 0, 0, 0);
                const int f = 16 * (4 * quad + fi) + m;
                uint2 o;
                o.x = f2bf_u(d[0]) | (f2bf_u(d[1]) << 16);   // t = 16tt+4q, +1
                o.y = f2bf_u(d[2]) | (f2bf_u(d[3]) << 16);   // t = 16tt+4q+2, +3
                *(uint2*)(yL + f * YWW + 8 * tt + 2 * q) = o;
            }
        }
        // zero the finite-pad cols 320..335 (multiplied by band zeros; must be finite)
        yL[(tid >> 3) * YWW + 160 + (tid & 7)] = 0u;
    }
    __syncthreads();

    // ---------- Phase 4: banded temporal MFMA, A-frags from yL (ds_read_b128) ----------
    float acc = 0.f;
    {
        float rr[4];
#pragma unroll
        for (int r = 0; r < 4; ++r) {
            int t = 64 * q + 16 * r + m;    // this lane's 4 output positions
            rr[r] = __uint_as_float(xT[33 * SXW + t]);   // 4-lane broadcast, conflict-free
        }
        const int f0t = 8 * w;
        uint4 pb0, pb1, pb2;
        {
            const uint4* bb = bandB + (size_t)f0t * 3 * 64;
            pb0 = bb[l]; pb1 = bb[64 + l]; pb2 = bb[128 + l];
        }
#pragma unroll 2
        for (int fi = 0; fi < 8; ++fi) {
            const int f = f0t + fi;
            FragU B0, B1, B2;
            B0.q4 = pb0; B1.q4 = pb1; B2.q4 = pb2;
            if (fi < 7) {                   // prefetch next filter's band (L2)
                const uint4* bb = bandB + (size_t)(f + 1) * 3 * 64;
                pb0 = bb[l]; pb1 = bb[64 + l]; pb2 = bb[128 + l];
            }
            const int abase = f * YWW + 8 * m + 4 * q;   // 16B-aligned u32 word index
            FragU a0, a1, a2;
            a0.q4 = *(const uint4*)(yL + abase);
            a1.q4 = *(const uint4*)(yL + abase + 16);
            a2.q4 = *(const uint4*)(yL + abase + 32);
            f32x4 d = {0.f, 0.f, 0.f, 0.f};
            d = __builtin_amdgcn_mfma_f32_16x16x32_bf16(a0.v, B0.v, d, 0, 0, 0);
            d = __builtin_amdgcn_mfma_f32_16x16x32_bf16(a1.v, B1.v, d, 0, 0, 0);
            d = __builtin_amdgcn_mfma_f32_16x16x32_bf16(a2.v, B2.v, d, 0, 0, 0);
            float facc = 0.f;
#pragma unroll
            for (int r = 0; r < 4; ++r) facc += fabsf(d[r]) * rr[r];
            acc += wnf[f] * facc;
        }
    }

    // ---------- block reduction + atomic ----------
    for (int off = 32; off > 0; off >>= 1) acc += __shfl_down(acc, off, 64);
    if (l == 0) wred[w] = acc;
    __syncthreads();
    if (tid == 0) {
        float s = 0.f;
#pragma unroll
        for (int i = 0; i < 16; ++i) s += wred[i];
        atomicAdd(out + b, s);
    }
    if (blockIdx.x == 0 && tid < FF) {
        float v = bias[tid];
        for (int off = 32; off > 0; off >>= 1) v += __shfl_down(v, off, 64);
        if ((tid & 63) == 0) atomicAdd(out + b, v);
    }
}

// --------- Fallback (no workspace): one block per (f,b), LDS rows ----------
__global__ __launch_bounds__(256) void k_naive(
    const float* __restrict__ x, const float* __restrict__ cw,
    const float* __restrict__ sw, const float* __restrict__ weight,
    const float* __restrict__ bias, float* __restrict__ out)
{
    __shared__ float yl[TS];
    __shared__ float ql[TS];
    __shared__ float wred[4];
    const int f = blockIdx.x, b = blockIdx.y, tid = threadIdx.x;
    for (int t = tid; t < TS; t += 256) {
        float a = 0.f, s = 0.f;
        for (int c = 0; c < CINN; ++c) {
            float v = x[((size_t)b * CINN + c) * TS + t];
            a += sw[(size_t)f * CINN + c] * v;
            s += v * v;
        }
        yl[t] = a; ql[t] = s;
    }
    __syncthreads();
    float acc = 0.f;
    for (int t = tid; t < TOUT; t += 256) {
        float cv = 0.f, sl = 0.f;
        for (int k = 0; k < KS; ++k) { cv += cw[(size_t)f * KS + k] * yl[t + k]; sl += ql[t + k]; }
        acc += fabsf(cv) * rsqrtf(sl);
    }
    float ssw = 0.f, scw = 0.f;
    for (int c = 0; c < CINN; ++c) { float v = sw[(size_t)f * CINN + c]; ssw += v * v; }
    for (int k = 0; k < KS; ++k)   { float v = cw[(size_t)f * KS + k];  scw += v * v; }
    const float wnf = weight[f] * rsqrtf(ssw * scw) * 64.0f / (float)TOUT;
    for (int off = 32; off > 0; off >>= 1) acc += __shfl_down(acc, off, 64);
    if ((tid & 63) == 0) wred[tid >> 6] = acc;
    __syncthreads();
    if (tid == 0) {
        float tot = (wred[0] + wred[1] + wred[2] + wred[3]) * wnf;
        if (f == 0) {
            float bsum = 0.f;
            for (int ff = 0; ff < FF; ++ff) bsum += bias[ff];
            tot += bsum;
        }
        atomicAdd(out + b, tot);
    }
}

extern "C" void kernel_launch(void* const* d_in, const int* in_sizes, int n_in,
                              void* d_out, int out_size, void* d_ws, size_t ws_size,
                              hipStream_t stream) {
    const float* x  = (const float*)d_in[0];
    const float* cw = (const float*)d_in[1];   // [F,K]
    const float* sw = (const float*)d_in[2];   // [F,CIN]
    const float* w  = (const float*)d_in[3];   // [F]
    const float* bs = (const float*)d_in[4];   // [F]
    float* out = (float*)d_out;

    hipMemsetAsync(d_out, 0, (size_t)out_size * sizeof(float), stream);

    const size_t bandBytes = (size_t)FF * 3 * 64 * 16;        // 384 KB
    const size_t wnBytes   = (size_t)FF * sizeof(float);
    const size_t swfBytes  = (size_t)(FF / 16) * 2 * 64 * 16; // 16 KB

    if (bandBytes + wnBytes + swfBytes <= ws_size) {
        uint4* bandB = (uint4*)d_ws;
        float* wnf   = (float*)((char*)d_ws + bandBytes);
        uint4* swF   = (uint4*)((char*)d_ws + bandBytes + wnBytes);
        k_band <<<dim3(FF), 64, 0, stream>>>(cw, sw, w, bandB, wnf, swF);
        k_fused<<<dim3(TS / TSEG, BB), 1024, 0, stream>>>(x, swF, bandB, wnf, bs, out);
    } else {
        k_naive<<<dim3(FF, BB), 256, 0, stream>>>(x, cw, sw, w, bs, out);
    }
}